// Round 1
// baseline (1099.635 us; speedup 1.0000x reference)
//
#include <hip/hip_runtime.h>
#include <math.h>

#define N_TOK 131072
#define VOCAB 50257
#define DIM   512
#define K_CON 512

// d_out layout (float32 elements)
#define OFF_ENC  ((size_t)0)
#define OFF_QW   ((size_t)67108864)
#define OFF_DOCU ((size_t)134217728)
#define OFF_OUT  ((size_t)134218240)
#define OFF_VQ   ((size_t)134268497)
#define OFF_LTS  ((size_t)134268498)

// ws layout (bytes)
#define WS_COUNTS 0        // 512 * u32
#define WS_VQ     2048     // double
#define WS_LTS    2056     // double
#define WS_MAXV   2064     // float
#define WS_SUMV   2072     // double
#define WS_NARR   4096     // 512 f32
#define WS_SARR   6144     // 512 f32
#define WS_BINC   8192     // VOCAB u32
#define WS_LOGITS 209920   // VOCAB f32

// ---------------------------------------------------------------------------
// n_j = |c_j|^2, s_j = sum(c_j)  (double-accumulated, rounded once to f32 so
// our fl(nx+n) matches the reference's fp32 n to <=1 ulp)
__global__ void k_ns(const float* __restrict__ cw, float* __restrict__ n_arr,
                     float* __restrict__ s_arr) {
    int w = threadIdx.x >> 6, lane = threadIdx.x & 63;
    int r = blockIdx.x * 4 + w;
    const float* row = cw + (size_t)r * DIM;
    float4 a = *(const float4*)(row + lane * 8);
    float4 b = *(const float4*)(row + lane * 8 + 4);
    float v[8] = {a.x,a.y,a.z,a.w,b.x,b.y,b.z,b.w};
    double na = 0.0, sa = 0.0;
    #pragma unroll
    for (int e = 0; e < 8; ++e) { na += (double)v[e]*v[e]; sa += (double)v[e]; }
    for (int off = 32; off; off >>= 1) {
        na += __shfl_down(na, off);
        sa += __shfl_down(sa, off);
    }
    if (lane == 0) { n_arr[r] = (float)na; s_arr[r] = (float)sa; }
}

// ---------------------------------------------------------------------------
// Main fused kernel: per block of 64 tokens:
//   - nx_t = |x_t|^2 (double->f32)
//   - fp32 tiled GEMM x@C^T with 8x8 register blocking, TT=64, KT=256, DK=32
//   - d2 = fmaf(-2, dot, fl(nx+n_j)) mimicking ref rounding; running argmin
//     with (value, index) lexicographic tie-break == jnp.argmin first-min
//   - epilogue: one-hot encodings write, quantized_words write, vq partial
//     (double), K-histogram atomics
__global__ __launch_bounds__(256, 2)
void k_main(const int* __restrict__ doc, const float* __restrict__ emb,
            const float* __restrict__ cw, const float* __restrict__ n_arr,
            float* __restrict__ out, unsigned* __restrict__ counts,
            double* __restrict__ vq_acc) {
    __shared__ float xs[32][68];    // [d][t], pad 68 -> staging writes 4-way
    __shared__ float cs[32][260];   // [d][k]
    __shared__ uint2 red[64][4];    // per-token per-wave (valbits, idx)
    __shared__ float ns_l[256];
    __shared__ float nxs[64];
    __shared__ double dred[256];
    __shared__ int docs[64];
    __shared__ int idxs[64];

    const int tid  = threadIdx.x;
    const int n0   = blockIdx.x * 64;
    const int toct = tid & 7;     // token octet: tokens 8*toct..+7
    const int koct = tid >> 3;    // concept octet 0..31
    const int wv   = tid >> 6;    // wave 0..3
    const int lane = tid & 63;

    if (tid < 64) docs[tid] = doc[n0 + tid];
    __syncthreads();

    // nx per token
    {
        int t = tid >> 2, q = tid & 3;
        const float* xr = emb + (size_t)docs[t] * DIM + q * 128;
        double px = 0.0;
        for (int f = 0; f < 32; ++f) {
            float4 v = *(const float4*)(xr + f * 4);
            px += (double)v.x*v.x + (double)v.y*v.y + (double)v.z*v.z + (double)v.w*v.w;
        }
        dred[tid] = px;
    }
    __syncthreads();
    if (tid < 64) {
        double s = dred[tid*4] + dred[tid*4+1] + dred[tid*4+2] + dred[tid*4+3];
        nxs[tid] = (float)s;
    }

    float rbv = INFINITY; int rbj = 0x7fffffff;   // running best (tid<64 only)

    for (int kc = 0; kc < 2; ++kc) {
        __syncthreads();
        ns_l[tid] = n_arr[kc * 256 + tid];

        float acc[8][8];
        #pragma unroll
        for (int i = 0; i < 8; ++i)
            #pragma unroll
            for (int j = 0; j < 8; ++j) acc[i][j] = 0.f;

        for (int dk = 0; dk < 16; ++dk) {
            __syncthreads();
            const int base_d = dk << 5;
            // stage x tile (gathered rows), transposed to [d][t]
            #pragma unroll
            for (int rep = 0; rep < 2; ++rep) {
                int lin = rep * 256 + tid;
                int t = lin >> 3, fq = lin & 7;
                float4 v = *(const float4*)(emb + (size_t)docs[t]*DIM + base_d + fq*4);
                xs[fq*4+0][t] = v.x; xs[fq*4+1][t] = v.y;
                xs[fq*4+2][t] = v.z; xs[fq*4+3][t] = v.w;
            }
            // stage c tile, transposed to [d][k]
            #pragma unroll
            for (int rep = 0; rep < 8; ++rep) {
                int lin = rep * 256 + tid;
                int k = lin >> 3, fq = lin & 7;
                float4 v = *(const float4*)(cw + (size_t)(kc*256 + k)*DIM + base_d + fq*4);
                cs[fq*4+0][k] = v.x; cs[fq*4+1][k] = v.y;
                cs[fq*4+2][k] = v.z; cs[fq*4+3][k] = v.w;
            }
            __syncthreads();
            #pragma unroll 2
            for (int d = 0; d < 32; ++d) {
                float4 xa = *(const float4*)&xs[d][toct*8];
                float4 xb = *(const float4*)&xs[d][toct*8+4];
                float4 ca = *(const float4*)&cs[d][koct*8];
                float4 cb = *(const float4*)&cs[d][koct*8+4];
                float xr[8] = {xa.x,xa.y,xa.z,xa.w,xb.x,xb.y,xb.z,xb.w};
                float cr[8] = {ca.x,ca.y,ca.z,ca.w,cb.x,cb.y,cb.z,cb.w};
                #pragma unroll
                for (int i = 0; i < 8; ++i)
                    #pragma unroll
                    for (int j = 0; j < 8; ++j)
                        acc[i][j] = fmaf(xr[i], cr[j], acc[i][j]);
            }
        }

        // epilogue: d2 + local argmin over this thread's 8 concepts, per token
        float bvv[8]; int bjj[8];
        #pragma unroll
        for (int i = 0; i < 8; ++i) {
            int t = toct*8 + i;
            float nx = nxs[t];
            float bv = INFINITY; int bj = 0x7fffffff;
            #pragma unroll
            for (int j = 0; j < 8; ++j) {
                float t1 = nx + ns_l[koct*8 + j];          // fl(nx + n_j) as ref
                float v  = fmaf(-2.f, acc[i][j], t1);      // fl(t1 - 2*dot) as ref
                int kg = kc*256 + koct*8 + j;
                if (v < bv) { bv = v; bj = kg; }           // ascending j: first min
            }
            bvv[i] = bv; bjj[i] = bj;
        }
        // butterfly across the wave's 8 koct groups (lane bits 3..5)
        #pragma unroll
        for (int i = 0; i < 8; ++i) {
            float bv = bvv[i]; int bj = bjj[i];
            for (int off = 8; off < 64; off <<= 1) {
                float ov = __shfl_xor(bv, off);
                int   oj = __shfl_xor(bj, off);
                if (ov < bv || (ov == bv && oj < bj)) { bv = ov; bj = oj; }
            }
            bvv[i] = bv; bjj[i] = bj;
        }
        if (lane < 8) {
            #pragma unroll
            for (int i = 0; i < 8; ++i)
                red[lane*8 + i][wv] = make_uint2(__float_as_uint(bvv[i]), (unsigned)bjj[i]);
        }
        __syncthreads();
        if (tid < 64) {
            #pragma unroll
            for (int w = 0; w < 4; ++w) {
                uint2 e = red[tid][w];
                float v = __uint_as_float(e.x); int j = (int)e.y;
                if (v < rbv || (v == rbv && j < rbj)) { rbv = v; rbj = j; }
            }
        }
    }

    if (tid < 64) { idxs[tid] = rbj; atomicAdd(&counts[rbj], 1u); }
    __syncthreads();

    // encodings: one-hot rows, written exactly once
    for (int lin = tid; lin < 8192; lin += 256) {
        int t = lin >> 7, f4 = lin & 127;
        int idx = idxs[t];
        float4 v = make_float4(0.f, 0.f, 0.f, 0.f);
        if ((idx >> 2) == f4) ((float*)&v)[idx & 3] = 1.0f;
        *(float4*)(out + OFF_ENC + ((size_t)(n0 + t) << 9) + (f4 << 2)) = v;
    }
    // quantized_words (= codebook rows) + vq partial
    double vql = 0.0;
    for (int lin = tid; lin < 8192; lin += 256) {
        int t = lin >> 7, f4 = lin & 127;
        const float* crow = cw  + (size_t)idxs[t] * DIM;
        const float* xrow = emb + (size_t)docs[t] * DIM;
        float4 c4 = *(const float4*)(crow + f4*4);
        float4 x4 = *(const float4*)(xrow + f4*4);
        *(float4*)(out + OFF_QW + ((size_t)(n0 + t) << 9) + (f4 << 2)) = c4;
        float dx = c4.x-x4.x, dy = c4.y-x4.y, dz = c4.z-x4.z, dw = c4.w-x4.w;
        vql += (double)dx*dx + (double)dy*dy + (double)dz*dz + (double)dw*dw;
    }
    dred[tid] = vql;
    __syncthreads();
    for (int s = 128; s; s >>= 1) {
        if (tid < s) dred[tid] += dred[tid + s];
        __syncthreads();
    }
    if (tid == 0) atomicAdd(vq_acc, dred[0]);
}

// ---------------------------------------------------------------------------
__global__ void k_binc(const int* __restrict__ doc, unsigned* __restrict__ binc) {
    int i = blockIdx.x * blockDim.x + threadIdx.x;
    if (i < N_TOK) atomicAdd(&binc[doc[i]], 1u);
}

// quantized_docu[d] = sum_j count_j * c[j][d] / N
__global__ void k_docu(const unsigned* __restrict__ counts,
                       const float* __restrict__ cw, float* __restrict__ out_docu) {
    __shared__ float cnt[512];
    int tid = threadIdx.x;
    cnt[tid] = (float)counts[tid];
    __syncthreads();
    double a = 0.0;
    for (int j = 0; j < K_CON; ++j)
        a += (double)cnt[j] * (double)cw[(size_t)j * DIM + tid];
    out_docu[tid] = (float)(a * (1.0 / (double)N_TOK));
}

// lts hinge over all KxK pairs; block = 4 i-rows
__global__ __launch_bounds__(256)
void k_lts(const float* __restrict__ cw, const float* __restrict__ n_arr,
           const float* __restrict__ s_arr, double* __restrict__ lts_acc) {
    __shared__ float ci[4 * 512];
    __shared__ float cjs[64 * 68];
    __shared__ double dred[256];
    const int tid = threadIdx.x;
    const int i0 = blockIdx.x * 4;
    #pragma unroll
    for (int rep = 0; rep < 2; ++rep) {
        int lin = rep * 256 + tid;
        int r = lin >> 7, fq = lin & 127;
        *(float4*)&ci[r*512 + fq*4] = *(const float4*)(cw + (size_t)(i0+r)*DIM + fq*4);
    }
    const int jj = tid & 63, ih = tid >> 6;
    const int ig = i0 + ih;
    const float ni = n_arr[ig], si = s_arr[ig];
    const float EPS = 1e-6f;
    double lsum = 0.0;
    for (int jc = 0; jc < 8; ++jc) {
        float accv = 0.f;
        for (int dc = 0; dc < 8; ++dc) {
            __syncthreads();
            #pragma unroll
            for (int rep = 0; rep < 4; ++rep) {
                int lin = rep * 256 + tid;
                int j = lin >> 4, fq = lin & 15;
                float4 v = *(const float4*)(cw + (size_t)(jc*64 + j)*DIM + dc*64 + fq*4);
                cjs[(fq*4+0)*68 + j] = v.x; cjs[(fq*4+1)*68 + j] = v.y;
                cjs[(fq*4+2)*68 + j] = v.z; cjs[(fq*4+3)*68 + j] = v.w;
            }
            __syncthreads();
            #pragma unroll 4
            for (int d = 0; d < 64; ++d)
                accv = fmaf(ci[ih*512 + dc*64 + d], cjs[d*68 + jj], accv);
        }
        int jg = jc*64 + jj;
        float dd = ni + n_arr[jg] - 2.f*accv + 2.f*EPS*(si - s_arr[jg]) + 512.f*EPS*EPS;
        float dist = sqrtf(fmaxf(dd, 0.f));
        lsum += (double)((ig == jg) ? dist : fmaxf(0.f, 1.f - dist));
    }
    dred[tid] = lsum;
    __syncthreads();
    for (int s = 128; s; s >>= 1) {
        if (tid < s) dred[tid] += dred[tid + s];
        __syncthreads();
    }
    if (tid == 0) atomicAdd(lts_acc, dred[0]);
}

// logits[v] = dot(docu, q2w[v]) + bias[v] ; wave per row
__global__ void k_logits(const float* __restrict__ docu, const float* __restrict__ q2w,
                         const float* __restrict__ q2b, float* __restrict__ logits) {
    int wvi = threadIdx.x >> 6, lane = threadIdx.x & 63;
    int v = blockIdx.x * 4 + wvi;
    if (v >= VOCAB) return;
    const float* wr = q2w + (size_t)v * DIM;
    float4 a = *(const float4*)(wr + lane*8);
    float4 b = *(const float4*)(wr + lane*8 + 4);
    float4 da = *(const float4*)(docu + lane*8);
    float4 db = *(const float4*)(docu + lane*8 + 4);
    float p = a.x*da.x + a.y*da.y + a.z*da.z + a.w*da.w
            + b.x*db.x + b.y*db.y + b.z*db.z + b.w*db.w;
    for (int off = 32; off; off >>= 1) p += __shfl_down(p, off);
    if (lane == 0) logits[v] = p + q2b[v];
}

__global__ void k_max(const float* __restrict__ logits, float* __restrict__ maxv) {
    __shared__ float red[1024];
    int tid = threadIdx.x;
    float m = -INFINITY;
    for (int i = tid; i < VOCAB; i += 1024) m = fmaxf(m, logits[i]);
    red[tid] = m; __syncthreads();
    for (int s = 512; s; s >>= 1) {
        if (tid < s) red[tid] = fmaxf(red[tid], red[tid + s]);
        __syncthreads();
    }
    if (tid == 0) *maxv = red[0];
}

__global__ void k_sum(const float* __restrict__ logits, const float* __restrict__ maxv,
                      double* __restrict__ sumv) {
    __shared__ double red[1024];
    int tid = threadIdx.x;
    float m = *maxv;
    double s = 0.0;
    for (int i = tid; i < VOCAB; i += 1024) s += (double)expf(logits[i] - m);
    red[tid] = s; __syncthreads();
    for (int st = 512; st; st >>= 1) {
        if (tid < st) red[tid] += red[tid + st];
        __syncthreads();
    }
    if (tid == 0) *sumv = red[0];
}

__global__ void k_final(const float* __restrict__ logits, const float* __restrict__ maxv,
                        const double* __restrict__ sumv, const unsigned* __restrict__ binc,
                        const double* __restrict__ vq_acc, const double* __restrict__ lts_acc,
                        float* __restrict__ out) {
    int v = blockIdx.x * 256 + threadIdx.x;
    if (v < VOCAB) {
        float m = *maxv;
        float s = (float)(*sumv);
        float p = expf(logits[v] - m) / s;
        out[OFF_OUT + v] = logf(p + 1e-6f) * (float)binc[v];
    }
    if (v == 0) {
        out[OFF_VQ]  = (float)(1.25 * (*vq_acc) * (1.0 / 67108864.0));
        out[OFF_LTS] = (float)((*lts_acc) * (1.0 / 262144.0));
    }
}

// ---------------------------------------------------------------------------
extern "C" void kernel_launch(void* const* d_in, const int* in_sizes, int n_in,
                              void* d_out, int out_size, void* d_ws, size_t ws_size,
                              hipStream_t stream) {
    const int*   doc = (const int*)d_in[0];
    const float* emb = (const float*)d_in[1];
    const float* cw  = (const float*)d_in[2];
    const float* q2w = (const float*)d_in[3];
    const float* q2b = (const float*)d_in[4];
    float* out = (float*)d_out;
    char* ws = (char*)d_ws;

    unsigned* counts = (unsigned*)(ws + WS_COUNTS);
    double*   vq_acc = (double*)(ws + WS_VQ);
    double*   lts_acc= (double*)(ws + WS_LTS);
    float*    maxv   = (float*)(ws + WS_MAXV);
    double*   sumv   = (double*)(ws + WS_SUMV);
    float*    n_arr  = (float*)(ws + WS_NARR);
    float*    s_arr  = (float*)(ws + WS_SARR);
    unsigned* binc   = (unsigned*)(ws + WS_BINC);
    float*    logits = (float*)(ws + WS_LOGITS);

    hipMemsetAsync(ws, 0, 4096, stream);
    hipMemsetAsync(binc, 0, VOCAB * sizeof(unsigned), stream);

    hipLaunchKernelGGL(k_ns,   dim3(128),  dim3(256), 0, stream, cw, n_arr, s_arr);
    hipLaunchKernelGGL(k_main, dim3(2048), dim3(256), 0, stream, doc, emb, cw, n_arr,
                       out, counts, vq_acc);
    hipLaunchKernelGGL(k_binc, dim3(512),  dim3(256), 0, stream, doc, binc);
    hipLaunchKernelGGL(k_docu, dim3(1),    dim3(512), 0, stream, counts, cw, out + OFF_DOCU);
    hipLaunchKernelGGL(k_lts,  dim3(128),  dim3(256), 0, stream, cw, n_arr, s_arr, lts_acc);
    hipLaunchKernelGGL(k_logits, dim3((VOCAB + 3) / 4), dim3(256), 0, stream,
                       out + OFF_DOCU, q2w, q2b, logits);
    hipLaunchKernelGGL(k_max,  dim3(1), dim3(1024), 0, stream, logits, maxv);
    hipLaunchKernelGGL(k_sum,  dim3(1), dim3(1024), 0, stream, logits, maxv, sumv);
    hipLaunchKernelGGL(k_final, dim3((VOCAB + 255) / 256), dim3(256), 0, stream,
                       logits, maxv, sumv, binc, vq_acc, lts_acc, out);
}

// Round 2
// 642.869 us; speedup vs baseline: 1.7105x; 1.7105x over previous
//
#include <hip/hip_runtime.h>
#include <math.h>

#define N_TOK 131072
#define VOCAB 50257
#define DIM   512
#define K_CON 512

// d_out layout (float32 elements)
#define OFF_ENC  ((size_t)0)
#define OFF_QW   ((size_t)67108864)
#define OFF_DOCU ((size_t)134217728)
#define OFF_OUT  ((size_t)134218240)
#define OFF_VQ   ((size_t)134268497)
#define OFF_LTS  ((size_t)134268498)

// ws layout (bytes)
#define WS_COUNTS 0        // 512 * u32
#define WS_VQ     2048     // double
#define WS_LTS    2056     // double
#define WS_MAXV   2064     // float
#define WS_SUMV   2072     // double
#define WS_NFLAG  2080     // u32
#define WS_NARR   4096     // 512 f32
#define WS_SARR   6144     // 512 f32
#define WS_BINC   8192     // VOCAB u32
#define WS_LOGITS 209920   // VOCAB f32
#define WS_FLAGS  411648   // FLAG_CAP u32
#define FLAG_CAP  8192

typedef __attribute__((ext_vector_type(8)))  short s16x8;
typedef __attribute__((ext_vector_type(16))) float f32x16;

// Codebook in bf16 hi/lo, MFMA-staging layout:
// tile per step s (16 fp32 dims): [g 0..3][concept 0..511] x s16x8
//   g = pass*2 + half ; pass 0 = hi, 1 = lo ; half selects dims s*16+half*8..+7
__device__ short g_B2[32 * 4 * 512 * 8];   // 1 MB

__device__ inline unsigned short f2bf(float f) {
    unsigned u = __float_as_uint(f);
    unsigned r = (u + 0x7fffu + ((u >> 16) & 1u)) >> 16;
    return (unsigned short)r;
}
__device__ inline float bf2f(unsigned short h) {
    return __uint_as_float(((unsigned)h) << 16);
}

__device__ inline void gload16(const void* g, void* l) {
    __builtin_amdgcn_global_load_lds(
        (const __attribute__((address_space(1))) unsigned int*)g,
        (__attribute__((address_space(3))) unsigned int*)l, 16, 0, 0);
}

// ---------------------------------------------------------------------------
__global__ void k_ns(const float* __restrict__ cw, float* __restrict__ n_arr,
                     float* __restrict__ s_arr) {
    int w = threadIdx.x >> 6, lane = threadIdx.x & 63;
    int r = blockIdx.x * 4 + w;
    const float* row = cw + (size_t)r * DIM;
    float4 a = *(const float4*)(row + lane * 8);
    float4 b = *(const float4*)(row + lane * 8 + 4);
    float v[8] = {a.x,a.y,a.z,a.w,b.x,b.y,b.z,b.w};
    double na = 0.0, sa = 0.0;
    #pragma unroll
    for (int e = 0; e < 8; ++e) { na += (double)v[e]*v[e]; sa += (double)v[e]; }
    for (int off = 32; off; off >>= 1) {
        na += __shfl_down(na, off);
        sa += __shfl_down(sa, off);
    }
    if (lane == 0) { n_arr[r] = (float)na; s_arr[r] = (float)sa; }
}

// ---------------------------------------------------------------------------
// Codebook -> bf16 hi/lo staging layout in g_B2
__global__ void k_prepb(const float* __restrict__ cw, short* __restrict__ b2) {
    int tid = threadIdx.x;
    int c = blockIdx.x * 4 + (tid >> 6);
    int t = tid & 63;
    int s = t >> 1, hf = t & 1;
    const float* p = cw + (size_t)c * DIM + s * 16 + hf * 8;
    float4 xa = *(const float4*)p;
    float4 xb = *(const float4*)(p + 4);
    float xf[8] = {xa.x,xa.y,xa.z,xa.w,xb.x,xb.y,xb.z,xb.w};
    s16x8 h8, l8;
    #pragma unroll
    for (int e = 0; e < 8; ++e) {
        unsigned short hb = f2bf(xf[e]);
        h8[e] = (short)hb;
        l8[e] = (short)f2bf(xf[e] - bf2f(hb));
    }
    size_t tb = (size_t)s * 16384;
    *(s16x8*)&b2[tb + ((size_t)(hf * 512 + c)) * 8]       = h8;
    *(s16x8*)&b2[tb + ((size_t)((2 + hf) * 512 + c)) * 8] = l8;
}

// ---------------------------------------------------------------------------
// Main: bf16-split MFMA distance GEMM (64 tokens x 512 concepts per block)
// + argmin with second-best tracking + provisional epilogue writes.
__global__ __launch_bounds__(256, 2)
void k_main(const int* __restrict__ doc, const float* __restrict__ emb,
            const float* __restrict__ cw, const float* __restrict__ n_arr,
            float* __restrict__ out, unsigned* __restrict__ counts,
            double* __restrict__ vq_acc, unsigned* __restrict__ nflag,
            unsigned* __restrict__ flag_list) {
    __shared__ s16x8 bshv[4 * 512];       // 32 KB: B tile [g][concept]
    __shared__ float nsl[512];
    __shared__ uint4 redv[2][64];
    __shared__ int docs[64];
    __shared__ int idxs[64];
    __shared__ double dred[256];

    short* bsh = (short*)bshv;
    const int tid  = threadIdx.x;
    const int n0   = blockIdx.x * 64;
    const int lane = tid & 63;
    const int wv   = tid >> 6;
    const int wm   = wv & 1;       // token half: 32 tokens
    const int wn   = wv >> 1;      // concept half: 256 concepts
    const int hv   = lane >> 5;    // k-half within fragment
    const int cb   = wn * 256 + (lane & 31);   // this lane's concept (+n*32)

    if (tid < 64) docs[tid] = doc[n0 + tid];
    nsl[tid]       = n_arr[tid];
    nsl[tid + 256] = n_arr[tid + 256];
    __syncthreads();

    const int mydoc = docs[wm * 32 + (lane & 31)];
    const float* xrow = emb + (size_t)mydoc * DIM;

    f32x16 acc[8];
    #pragma unroll
    for (int n = 0; n < 8; ++n) acc[n] = (f32x16)(0.0f);

    double nxp = 0.0;

    for (int s = 0; s < 32; ++s) {
        __syncthreads();   // prev compute done -> safe to overwrite bsh
        // stage B tile for step s (linear 32 KB copy)
        {
            const char* b2t = (const char*)(g_B2 + (size_t)s * 16384);
            #pragma unroll
            for (int i = 0; i < 8; ++i)
                gload16(b2t + i * 4096 + wv * 1024 + lane * 16,
                        (char*)bsh + i * 4096 + wv * 1024);
        }
        // A: load 8 fp32 dims for this lane's token, convert to hi/lo frags
        const float* px = xrow + s * 16 + hv * 8;
        float4 xa = *(const float4*)px;
        float4 xb = *(const float4*)(px + 4);
        float xf[8] = {xa.x,xa.y,xa.z,xa.w,xb.x,xb.y,xb.z,xb.w};
        s16x8 ah, al;
        #pragma unroll
        for (int e = 0; e < 8; ++e) {
            unsigned short hb = f2bf(xf[e]);
            ah[e] = (short)hb;
            al[e] = (short)f2bf(xf[e] - bf2f(hb));
            nxp += (double)xf[e] * xf[e];
        }
        __syncthreads();   // barrier drains vmcnt(0) -> B tile staged
        #pragma unroll
        for (int n = 0; n < 8; ++n) {
            s16x8 bh = *(const s16x8*)(bsh + ((size_t)(hv * 512 + cb + n * 32)) * 8);
            s16x8 bl = *(const s16x8*)(bsh + ((size_t)((2 + hv) * 512 + cb + n * 32)) * 8);
            acc[n] = __builtin_amdgcn_mfma_f32_32x32x16_bf16(ah, bh, acc[n], 0, 0, 0);
            acc[n] = __builtin_amdgcn_mfma_f32_32x32x16_bf16(ah, bl, acc[n], 0, 0, 0);
            acc[n] = __builtin_amdgcn_mfma_f32_32x32x16_bf16(al, bh, acc[n], 0, 0, 0);
        }
    }

    // nx: combine the two k-halves (lane and lane^32 hold same token)
    double nxo = __shfl_xor(nxp, 32);
    float nxf = (float)(nxp + nxo);

    float nsv[8];
    #pragma unroll
    for (int n = 0; n < 8; ++n) nsv[n] = nsl[cb + n * 32];

    // per-row argmin + second best; C/D: col=lane&31, row=(r&3)+8*(r>>2)+4*hv
    #pragma unroll
    for (int r = 0; r < 16; ++r) {
        int tt = (r & 3) + ((r >> 2) << 3) + (hv << 2);   // 0..31 within wm
        float nxr = __shfl(nxf, tt);
        float v1 = INFINITY, v2 = INFINITY; int j1 = 0x7fffffff;
        #pragma unroll
        for (int n = 0; n < 8; ++n) {
            float d = fmaf(-2.f, acc[n][r], nxr + nsv[n]);
            int jj = cb + n * 32;
            if (d < v1) { v2 = v1; v1 = d; j1 = jj; }
            else if (d < v2) { v2 = d; }
        }
        #pragma unroll
        for (int off = 1; off < 32; off <<= 1) {
            float ov1 = __shfl_xor(v1, off);
            int   oj1 = __shfl_xor(j1, off);
            float ov2 = __shfl_xor(v2, off);
            v2 = fminf(fminf(v2, ov2), fmaxf(v1, ov1));
            bool take = (ov1 < v1) || (ov1 == v1 && oj1 < j1);
            if (take) { v1 = ov1; j1 = oj1; }
        }
        if ((lane & 31) == 0)
            redv[wn][wm * 32 + tt] = make_uint4(__float_as_uint(v1), (unsigned)j1,
                                                __float_as_uint(v2), 0u);
    }
    __syncthreads();
    if (tid < 64) {
        uint4 a = redv[0][tid], b = redv[1][tid];
        float av1 = __uint_as_float(a.x), bv1 = __uint_as_float(b.x);
        float av2 = __uint_as_float(a.z), bv2 = __uint_as_float(b.z);
        float v2 = fminf(fminf(av2, bv2), fmaxf(av1, bv1));
        bool take = (bv1 < av1) || (bv1 == av1 && (int)b.y < (int)a.y);
        float v1 = take ? bv1 : av1;
        int   j1 = take ? (int)b.y : (int)a.y;
        idxs[tid] = j1;
        atomicAdd(&counts[j1], 1u);
        if (v2 - v1 <= 2e-7f) {           // near-tie: exact recompute later
            unsigned p = atomicAdd(nflag, 1u);
            if (p < FLAG_CAP) flag_list[p] = (unsigned)(n0 + tid);
        }
    }
    __syncthreads();

    // encodings: one-hot rows
    for (int lin = tid; lin < 8192; lin += 256) {
        int t = lin >> 7, f4 = lin & 127;
        int idx = idxs[t];
        float4 v = make_float4(0.f, 0.f, 0.f, 0.f);
        if ((idx >> 2) == f4) ((float*)&v)[idx & 3] = 1.0f;
        *(float4*)(out + OFF_ENC + ((size_t)(n0 + t) << 9) + (f4 << 2)) = v;
    }
    // quantized_words + vq partial
    double vql = 0.0;
    for (int lin = tid; lin < 8192; lin += 256) {
        int t = lin >> 7, f4 = lin & 127;
        const float* crow = cw  + (size_t)idxs[t] * DIM;
        const float* xr2  = emb + (size_t)docs[t] * DIM;
        float4 c4 = *(const float4*)(crow + f4*4);
        float4 x4 = *(const float4*)(xr2 + f4*4);
        *(float4*)(out + OFF_QW + ((size_t)(n0 + t) << 9) + (f4 << 2)) = c4;
        float dx = c4.x-x4.x, dy = c4.y-x4.y, dz = c4.z-x4.z, dw = c4.w-x4.w;
        vql += (double)dx*dx + (double)dy*dy + (double)dz*dz + (double)dw*dw;
    }
    dred[tid] = vql;
    __syncthreads();
    for (int st = 128; st; st >>= 1) {
        if (tid < st) dred[tid] += dred[tid + st];
        __syncthreads();
    }
    if (tid == 0) atomicAdd(vq_acc, dred[0]);
}

// ---------------------------------------------------------------------------
// Exact fp32 recompute (bit-identical to round-1 semantics) for flagged tokens;
// patches encodings / quantized / counts / vq in place.
__global__ __launch_bounds__(512)
void k_fixup(const int* __restrict__ doc, const float* __restrict__ emb,
             const float* __restrict__ cw, const float* __restrict__ n_arr,
             const unsigned* __restrict__ nflag, const unsigned* __restrict__ flag_list,
             float* __restrict__ out, unsigned* __restrict__ counts,
             double* __restrict__ vq_acc) {
    __shared__ float xs[512];
    __shared__ float nxsh;
    __shared__ int oldj_sh;
    __shared__ unsigned long long keys[512];
    __shared__ double dd[512];

    const int tid = threadIdx.x;
    unsigned nf = *nflag;
    if (nf > FLAG_CAP) nf = FLAG_CAP;

    for (unsigned f = blockIdx.x; f < nf; f += gridDim.x) {
        int t = (int)flag_list[f];
        int dc = doc[t];
        if (tid < 128)
            *(float4*)&xs[tid * 4] = *(const float4*)(emb + (size_t)dc * DIM + tid * 4);
        if (tid == 0) oldj_sh = -1;
        __syncthreads();
        if (tid == 0) {
            // nx exactly as round-1: 4 ordered double partials over 128-dim chunks
            double p[4];
            for (int q = 0; q < 4; ++q) {
                double px = 0.0;
                for (int fq = 0; fq < 32; ++fq) {
                    float4 v = *(const float4*)&xs[q * 128 + fq * 4];
                    px += (double)v.x*v.x + (double)v.y*v.y + (double)v.z*v.z + (double)v.w*v.w;
                }
                p[q] = px;
            }
            nxsh = (float)(((p[0] + p[1]) + p[2]) + p[3]);
        }
        // find old index from the one-hot row
        {
            float e = out[OFF_ENC + (size_t)t * 512 + tid];
            if (e == 1.0f) oldj_sh = tid;
        }
        __syncthreads();
        // exact distance, ascending-d fmaf chain (round-1 order)
        {
            const float* cr = cw + (size_t)tid * DIM;
            float dot = 0.f;
            for (int d = 0; d < 512; ++d) dot = fmaf(xs[d], cr[d], dot);
            float v = fmaf(-2.f, dot, nxsh + n_arr[tid]);
            keys[tid] = (((unsigned long long)__float_as_uint(v)) << 32) | (unsigned)tid;
        }
        __syncthreads();
        for (int st = 256; st; st >>= 1) {
            if (tid < st) {
                unsigned long long o = keys[tid + st];
                if (o < keys[tid]) keys[tid] = o;
            }
            __syncthreads();
        }
        int newj = (int)(keys[0] & 0xffffffffu);
        int oldj = oldj_sh;
        if (newj != oldj) {
            // patch encodings
            if (tid == 0) {
                out[OFF_ENC + (size_t)t * 512 + oldj] = 0.0f;
                out[OFF_ENC + (size_t)t * 512 + newj] = 1.0f;
                atomicSub(&counts[oldj], 1u);
                atomicAdd(&counts[newj], 1u);
            }
            // patch quantized row + vq delta
            double part = 0.0;
            if (tid < 128) {
                float4 cn = *(const float4*)(cw + (size_t)newj * DIM + tid * 4);
                float4 co = *(const float4*)(cw + (size_t)oldj * DIM + tid * 4);
                float4 x4 = *(const float4*)&xs[tid * 4];
                *(float4*)&out[OFF_QW + (size_t)t * 512 + tid * 4] = cn;
                float a0 = cn.x-x4.x, a1 = cn.y-x4.y, a2 = cn.z-x4.z, a3 = cn.w-x4.w;
                float b0 = co.x-x4.x, b1 = co.y-x4.y, b2 = co.z-x4.z, b3 = co.w-x4.w;
                part = ((double)a0*a0 + (double)a1*a1 + (double)a2*a2 + (double)a3*a3)
                     - ((double)b0*b0 + (double)b1*b1 + (double)b2*b2 + (double)b3*b3);
            }
            dd[tid] = part;
            __syncthreads();
            for (int st = 256; st; st >>= 1) {
                if (tid < st) dd[tid] += dd[tid + st];
                __syncthreads();
            }
            if (tid == 0) atomicAdd(vq_acc, dd[0]);
        }
        __syncthreads();
    }
}

// ---------------------------------------------------------------------------
__global__ void k_binc(const int* __restrict__ doc, unsigned* __restrict__ binc) {
    int i = blockIdx.x * blockDim.x + threadIdx.x;
    if (i < N_TOK) atomicAdd(&binc[doc[i]], 1u);
}

__global__ void k_docu(const unsigned* __restrict__ counts,
                       const float* __restrict__ cw, float* __restrict__ out_docu) {
    __shared__ float cnt[512];
    int tid = threadIdx.x;
    cnt[tid] = (float)counts[tid];
    __syncthreads();
    double a = 0.0;
    for (int j = 0; j < K_CON; ++j)
        a += (double)cnt[j] * (double)cw[(size_t)j * DIM + tid];
    out_docu[tid] = (float)(a * (1.0 / (double)N_TOK));
}

__global__ __launch_bounds__(256)
void k_lts(const float* __restrict__ cw, const float* __restrict__ n_arr,
           const float* __restrict__ s_arr, double* __restrict__ lts_acc) {
    __shared__ float ci[4 * 512];
    __shared__ float cjs[64 * 68];
    __shared__ double dred[256];
    const int tid = threadIdx.x;
    const int i0 = blockIdx.x * 4;
    #pragma unroll
    for (int rep = 0; rep < 2; ++rep) {
        int lin = rep * 256 + tid;
        int r = lin >> 7, fq = lin & 127;
        *(float4*)&ci[r*512 + fq*4] = *(const float4*)(cw + (size_t)(i0+r)*DIM + fq*4);
    }
    const int jj = tid & 63, ih = tid >> 6;
    const int ig = i0 + ih;
    const float ni = n_arr[ig], si = s_arr[ig];
    const float EPS = 1e-6f;
    double lsum = 0.0;
    for (int jc = 0; jc < 8; ++jc) {
        float accv = 0.f;
        for (int dc = 0; dc < 8; ++dc) {
            __syncthreads();
            #pragma unroll
            for (int rep = 0; rep < 4; ++rep) {
                int lin = rep * 256 + tid;
                int j = lin >> 4, fq = lin & 15;
                float4 v = *(const float4*)(cw + (size_t)(jc*64 + j)*DIM + dc*64 + fq*4);
                cjs[(fq*4+0)*68 + j] = v.x; cjs[(fq*4+1)*68 + j] = v.y;
                cjs[(fq*4+2)*68 + j] = v.z; cjs[(fq*4+3)*68 + j] = v.w;
            }
            __syncthreads();
            #pragma unroll 4
            for (int d = 0; d < 64; ++d)
                accv = fmaf(ci[ih*512 + dc*64 + d], cjs[d*68 + jj], accv);
        }
        int jg = jc*64 + jj;
        float ddv = ni + n_arr[jg] - 2.f*accv + 2.f*EPS*(si - s_arr[jg]) + 512.f*EPS*EPS;
        float dist = sqrtf(fmaxf(ddv, 0.f));
        lsum += (double)((ig == jg) ? dist : fmaxf(0.f, 1.f - dist));
    }
    dred[tid] = lsum;
    __syncthreads();
    for (int s = 128; s; s >>= 1) {
        if (tid < s) dred[tid] += dred[tid + s];
        __syncthreads();
    }
    if (tid == 0) atomicAdd(lts_acc, dred[0]);
}

__global__ void k_logits(const float* __restrict__ docu, const float* __restrict__ q2w,
                         const float* __restrict__ q2b, float* __restrict__ logits) {
    int wvi = threadIdx.x >> 6, lane = threadIdx.x & 63;
    int v = blockIdx.x * 4 + wvi;
    if (v >= VOCAB) return;
    const float* wr = q2w + (size_t)v * DIM;
    float4 a = *(const float4*)(wr + lane*8);
    float4 b = *(const float4*)(wr + lane*8 + 4);
    float4 da = *(const float4*)(docu + lane*8);
    float4 db = *(const float4*)(docu + lane*8 + 4);
    float p = a.x*da.x + a.y*da.y + a.z*da.z + a.w*da.w
            + b.x*db.x + b.y*db.y + b.z*db.z + b.w*db.w;
    for (int off = 32; off; off >>= 1) p += __shfl_down(p, off);
    if (lane == 0) logits[v] = p + q2b[v];
}

__global__ void k_max(const float* __restrict__ logits, float* __restrict__ maxv) {
    __shared__ float red[1024];
    int tid = threadIdx.x;
    float m = -INFINITY;
    for (int i = tid; i < VOCAB; i += 1024) m = fmaxf(m, logits[i]);
    red[tid] = m; __syncthreads();
    for (int s = 512; s; s >>= 1) {
        if (tid < s) red[tid] = fmaxf(red[tid], red[tid + s]);
        __syncthreads();
    }
    if (tid == 0) *maxv = red[0];
}

__global__ void k_sum(const float* __restrict__ logits, const float* __restrict__ maxv,
                      double* __restrict__ sumv) {
    __shared__ double red[1024];
    int tid = threadIdx.x;
    float m = *maxv;
    double s = 0.0;
    for (int i = tid; i < VOCAB; i += 1024) s += (double)expf(logits[i] - m);
    red[tid] = s; __syncthreads();
    for (int st = 512; st; st >>= 1) {
        if (tid < st) red[tid] += red[tid + st];
        __syncthreads();
    }
    if (tid == 0) *sumv = red[0];
}

__global__ void k_final(const float* __restrict__ logits, const float* __restrict__ maxv,
                        const double* __restrict__ sumv, const unsigned* __restrict__ binc,
                        const double* __restrict__ vq_acc, const double* __restrict__ lts_acc,
                        float* __restrict__ out) {
    int v = blockIdx.x * 256 + threadIdx.x;
    if (v < VOCAB) {
        float m = *maxv;
        float s = (float)(*sumv);
        float p = expf(logits[v] - m) / s;
        out[OFF_OUT + v] = logf(p + 1e-6f) * (float)binc[v];
    }
    if (v == 0) {
        out[OFF_VQ]  = (float)(1.25 * (*vq_acc) * (1.0 / 67108864.0));
        out[OFF_LTS] = (float)((*lts_acc) * (1.0 / 262144.0));
    }
}

// ---------------------------------------------------------------------------
extern "C" void kernel_launch(void* const* d_in, const int* in_sizes, int n_in,
                              void* d_out, int out_size, void* d_ws, size_t ws_size,
                              hipStream_t stream) {
    const int*   doc = (const int*)d_in[0];
    const float* emb = (const float*)d_in[1];
    const float* cw  = (const float*)d_in[2];
    const float* q2w = (const float*)d_in[3];
    const float* q2b = (const float*)d_in[4];
    float* out = (float*)d_out;
    char* ws = (char*)d_ws;

    unsigned* counts = (unsigned*)(ws + WS_COUNTS);
    double*   vq_acc = (double*)(ws + WS_VQ);
    double*   lts_acc= (double*)(ws + WS_LTS);
    float*    maxv   = (float*)(ws + WS_MAXV);
    double*   sumv   = (double*)(ws + WS_SUMV);
    unsigned* nflag  = (unsigned*)(ws + WS_NFLAG);
    float*    n_arr  = (float*)(ws + WS_NARR);
    float*    s_arr  = (float*)(ws + WS_SARR);
    unsigned* binc   = (unsigned*)(ws + WS_BINC);
    float*    logits = (float*)(ws + WS_LOGITS);
    unsigned* flags  = (unsigned*)(ws + WS_FLAGS);

    short* b2;
    hipGetSymbolAddress((void**)&b2, HIP_SYMBOL(g_B2));

    hipMemsetAsync(ws, 0, 4096, stream);
    hipMemsetAsync(binc, 0, VOCAB * sizeof(unsigned), stream);

    hipLaunchKernelGGL(k_ns,    dim3(128),  dim3(256), 0, stream, cw, n_arr, s_arr);
    hipLaunchKernelGGL(k_prepb, dim3(128),  dim3(256), 0, stream, cw, b2);
    hipLaunchKernelGGL(k_main,  dim3(2048), dim3(256), 0, stream, doc, emb, cw, n_arr,
                       out, counts, vq_acc, nflag, flags);
    hipLaunchKernelGGL(k_fixup, dim3(64),   dim3(512), 0, stream, doc, emb, cw, n_arr,
                       nflag, flags, out, counts, vq_acc);
    hipLaunchKernelGGL(k_binc,  dim3(512),  dim3(256), 0, stream, doc, binc);
    hipLaunchKernelGGL(k_docu,  dim3(1),    dim3(512), 0, stream, counts, cw, out + OFF_DOCU);
    hipLaunchKernelGGL(k_lts,   dim3(128),  dim3(256), 0, stream, cw, n_arr, s_arr, lts_acc);
    hipLaunchKernelGGL(k_logits, dim3((VOCAB + 3) / 4), dim3(256), 0, stream,
                       out + OFF_DOCU, q2w, q2b, logits);
    hipLaunchKernelGGL(k_max,   dim3(1), dim3(1024), 0, stream, logits, maxv);
    hipLaunchKernelGGL(k_sum,   dim3(1), dim3(1024), 0, stream, logits, maxv, sumv);
    hipLaunchKernelGGL(k_final, dim3((VOCAB + 255) / 256), dim3(256), 0, stream,
                       logits, maxv, sumv, binc, vq_acc, lts_acc, out);
}

// Round 3
// 579.343 us; speedup vs baseline: 1.8981x; 1.1097x over previous
//
#include <hip/hip_runtime.h>
#include <math.h>

#define N_TOK 131072
#define VOCAB 50257
#define DIM   512
#define K_CON 512

// d_out layout (float32 elements)
#define OFF_ENC  ((size_t)0)
#define OFF_QW   ((size_t)67108864)
#define OFF_DOCU ((size_t)134217728)
#define OFF_OUT  ((size_t)134218240)
#define OFF_VQ   ((size_t)134268497)
#define OFF_LTS  ((size_t)134268498)

// ws layout (bytes)
#define WS_COUNTS 0        // 512 * u32
#define WS_VQ     2048     // double
#define WS_LTS    2056     // double
#define WS_MAXV   2064     // float
#define WS_SUMV   2072     // double
#define WS_NFLAG  2080     // u32
#define WS_NARR   4096     // 512 f32
#define WS_SARR   6144     // 512 f32
#define WS_BINC   8192     // VOCAB u32
#define WS_LOGITS 209920   // VOCAB f32
#define WS_FLAGS  411648   // FLAG_CAP u32
#define FLAG_CAP  8192

typedef __attribute__((ext_vector_type(4)))  float f32x4;
typedef __attribute__((ext_vector_type(8)))  short s16x8;
typedef __attribute__((ext_vector_type(16))) float f32x16;

// Codebook in bf16 hi/lo, MFMA-staging layout:
// tile per step s (16 fp32 dims): [g 0..3][concept 0..511] x s16x8
//   g = pass*2 + half ; pass 0 = hi, 1 = lo ; half selects dims s*16+half*8..+7
__device__ short g_B2[32 * 4 * 512 * 8];   // 1 MB

__device__ inline unsigned short f2bf(float f) {
    unsigned u = __float_as_uint(f);
    unsigned r = (u + 0x7fffu + ((u >> 16) & 1u)) >> 16;
    return (unsigned short)r;
}
__device__ inline float bf2f(unsigned short h) {
    return __uint_as_float(((unsigned)h) << 16);
}

__device__ inline void gload16(const void* g, void* l) {
    __builtin_amdgcn_global_load_lds(
        (const __attribute__((address_space(1))) unsigned int*)g,
        (__attribute__((address_space(3))) unsigned int*)l, 16, 0, 0);
}

// ---------------------------------------------------------------------------
__global__ void k_ns(const float* __restrict__ cw, float* __restrict__ n_arr,
                     float* __restrict__ s_arr) {
    int w = threadIdx.x >> 6, lane = threadIdx.x & 63;
    int r = blockIdx.x * 4 + w;
    const float* row = cw + (size_t)r * DIM;
    float4 a = *(const float4*)(row + lane * 8);
    float4 b = *(const float4*)(row + lane * 8 + 4);
    float v[8] = {a.x,a.y,a.z,a.w,b.x,b.y,b.z,b.w};
    double na = 0.0, sa = 0.0;
    #pragma unroll
    for (int e = 0; e < 8; ++e) { na += (double)v[e]*v[e]; sa += (double)v[e]; }
    for (int off = 32; off; off >>= 1) {
        na += __shfl_down(na, off);
        sa += __shfl_down(sa, off);
    }
    if (lane == 0) { n_arr[r] = (float)na; s_arr[r] = (float)sa; }
}

// ---------------------------------------------------------------------------
// Codebook -> bf16 hi/lo staging layout in g_B2
__global__ void k_prepb(const float* __restrict__ cw, short* __restrict__ b2) {
    int tid = threadIdx.x;
    int c = blockIdx.x * 4 + (tid >> 6);
    int t = tid & 63;
    int s = t >> 1, hf = t & 1;
    const float* p = cw + (size_t)c * DIM + s * 16 + hf * 8;
    float4 xa = *(const float4*)p;
    float4 xb = *(const float4*)(p + 4);
    float xf[8] = {xa.x,xa.y,xa.z,xa.w,xb.x,xb.y,xb.z,xb.w};
    s16x8 h8, l8;
    #pragma unroll
    for (int e = 0; e < 8; ++e) {
        unsigned short hb = f2bf(xf[e]);
        h8[e] = (short)hb;
        l8[e] = (short)f2bf(xf[e] - bf2f(hb));
    }
    size_t tb = (size_t)s * 16384;
    *(s16x8*)&b2[tb + ((size_t)(hf * 512 + c)) * 8]       = h8;
    *(s16x8*)&b2[tb + ((size_t)((2 + hf) * 512 + c)) * 8] = l8;
}

// ---------------------------------------------------------------------------
// Main: bf16-split MFMA distance GEMM, double-buffered B staging with
// prefetch (1 barrier/step), A register prefetch, nx pre-pass, vq from v1.
__global__ __launch_bounds__(256, 2)
void k_main(const int* __restrict__ doc, const float* __restrict__ emb,
            const float* __restrict__ cw, const float* __restrict__ n_arr,
            float* __restrict__ out, unsigned* __restrict__ counts,
            double* __restrict__ vq_acc, unsigned* __restrict__ nflag,
            unsigned* __restrict__ flag_list) {
    __shared__ s16x8 bshv[2][4 * 512];    // 64 KB double-buffered B tile
    __shared__ float nsl[512];
    __shared__ float nxs[64];
    __shared__ uint4 redv[2][64];
    __shared__ int docs[64];
    __shared__ int idxs[64];
    __shared__ double dred[256];

    const int tid  = threadIdx.x;
    const int n0   = blockIdx.x * 64;
    const int lane = tid & 63;
    const int wv   = tid >> 6;
    const int wm   = wv & 1;       // token half: 32 tokens
    const int wn   = wv >> 1;      // concept half: 256 concepts
    const int hv   = lane >> 5;    // k-half within fragment
    const int cb   = wn * 256 + (lane & 31);

    if (tid < 64) docs[tid] = doc[n0 + tid];
    nsl[tid]       = n_arr[tid];
    nsl[tid + 256] = n_arr[tid + 256];
    __syncthreads();

    // stage B step 0 into buf 0 (issued early; drained by next barrier)
    {
        const char* b2t = (const char*)g_B2;
        char* dst = (char*)bshv[0];
        #pragma unroll
        for (int i = 0; i < 8; ++i)
            gload16(b2t + ((i * 4 + wv) << 10) + (lane << 4),
                    dst + ((i * 4 + wv) << 10));
    }

    // nx pre-pass: 4 threads per token, double partials
    {
        int t = tid >> 2, q = tid & 3;
        const float* xr = emb + (size_t)docs[t] * DIM + q * 128;
        double px = 0.0;
        for (int f = 0; f < 32; ++f) {
            float4 v = *(const float4*)(xr + f * 4);
            px += (double)v.x*v.x + (double)v.y*v.y + (double)v.z*v.z + (double)v.w*v.w;
        }
        dred[tid] = px;
    }

    const int mydoc = docs[wm * 32 + (lane & 31)];
    const float* xrow = emb + (size_t)mydoc * DIM;
    // prefetch A step 0
    float4 xa = *(const float4*)(xrow + hv * 8);
    float4 xb = *(const float4*)(xrow + hv * 8 + 4);

    __syncthreads();   // dred ready + B buf0 staged (vmcnt drained)
    if (tid < 64)
        nxs[tid] = (float)(dred[tid*4] + dred[tid*4+1] + dred[tid*4+2] + dred[tid*4+3]);

    f32x16 acc[8];
    #pragma unroll
    for (int n = 0; n < 8; ++n) acc[n] = (f32x16)(0.0f);

    int cur = 0;
    #pragma unroll 2
    for (int s = 0; s < 32; ++s) {
        // issue next-tile staging FIRST: full MFMA phase to complete
        if (s < 31) {
            const char* b2t = (const char*)(g_B2 + (size_t)(s + 1) * 16384);
            char* dst = (char*)bshv[cur ^ 1];
            #pragma unroll
            for (int i = 0; i < 8; ++i)
                gload16(b2t + ((i * 4 + wv) << 10) + (lane << 4),
                        dst + ((i * 4 + wv) << 10));
        }
        // convert prefetched A to hi/lo fragments
        float xf[8] = {xa.x,xa.y,xa.z,xa.w,xb.x,xb.y,xb.z,xb.w};
        s16x8 ah, al;
        #pragma unroll
        for (int e = 0; e < 8; ++e) {
            unsigned short hb = f2bf(xf[e]);
            ah[e] = (short)hb;
            al[e] = (short)f2bf(xf[e] - bf2f(hb));
        }
        // prefetch next A
        if (s < 31) {
            const float* px = xrow + (s + 1) * 16 + hv * 8;
            xa = *(const float4*)px;
            xb = *(const float4*)(px + 4);
        }
        // MFMA on current buffer
        const s16x8* bb = bshv[cur];
        #pragma unroll
        for (int n = 0; n < 8; ++n) {
            s16x8 bh = bb[hv * 512 + cb + n * 32];
            s16x8 bl = bb[(2 + hv) * 512 + cb + n * 32];
            acc[n] = __builtin_amdgcn_mfma_f32_32x32x16_bf16(ah, bh, acc[n], 0, 0, 0);
            acc[n] = __builtin_amdgcn_mfma_f32_32x32x16_bf16(ah, bl, acc[n], 0, 0, 0);
            acc[n] = __builtin_amdgcn_mfma_f32_32x32x16_bf16(al, bh, acc[n], 0, 0, 0);
        }
        __syncthreads();   // drains staging vmcnt; buf cur reads complete
        cur ^= 1;
    }

    float nsv[8];
    #pragma unroll
    for (int n = 0; n < 8; ++n) nsv[n] = nsl[cb + n * 32];

    // per-row argmin + second best; C/D: col=lane&31, row=(r&3)+8*(r>>2)+4*hv
    #pragma unroll
    for (int r = 0; r < 16; ++r) {
        int tt = (r & 3) + ((r >> 2) << 3) + (hv << 2);   // 0..31 within wm
        float nxr = nxs[wm * 32 + tt];
        float v1 = INFINITY, v2 = INFINITY; int j1 = 0x7fffffff;
        #pragma unroll
        for (int n = 0; n < 8; ++n) {
            float d = fmaf(-2.f, acc[n][r], nxr + nsv[n]);
            int jj = cb + n * 32;
            if (d < v1) { v2 = v1; v1 = d; j1 = jj; }
            else if (d < v2) { v2 = d; }
        }
        #pragma unroll
        for (int off = 1; off < 32; off <<= 1) {
            float ov1 = __shfl_xor(v1, off);
            int   oj1 = __shfl_xor(j1, off);
            float ov2 = __shfl_xor(v2, off);
            v2 = fminf(fminf(v2, ov2), fmaxf(v1, ov1));
            bool take = (ov1 < v1) || (ov1 == v1 && oj1 < j1);
            if (take) { v1 = ov1; j1 = oj1; }
        }
        if ((lane & 31) == 0)
            redv[wn][wm * 32 + tt] = make_uint4(__float_as_uint(v1), (unsigned)j1,
                                                __float_as_uint(v2), 0u);
    }
    __syncthreads();
    double myv1 = 0.0;
    if (tid < 64) {
        uint4 a = redv[0][tid], b = redv[1][tid];
        float av1 = __uint_as_float(a.x), bv1 = __uint_as_float(b.x);
        float av2 = __uint_as_float(a.z), bv2 = __uint_as_float(b.z);
        float v2 = fminf(fminf(av2, bv2), fmaxf(av1, bv1));
        bool take = (bv1 < av1) || (bv1 == av1 && (int)b.y < (int)a.y);
        float v1 = take ? bv1 : av1;
        int   j1 = take ? (int)b.y : (int)a.y;
        idxs[tid] = j1;
        atomicAdd(&counts[j1], 1u);
        myv1 = (double)v1;     // vq contribution = min squared distance
        if (v2 - v1 <= 2e-7f) {
            unsigned p = atomicAdd(nflag, 1u);
            if (p < FLAG_CAP) flag_list[p] = (unsigned)(n0 + tid);
        }
    }
    dred[tid] = myv1;
    __syncthreads();

    // encodings: one-hot rows (nontemporal — pure streaming output)
    for (int lin = tid; lin < 8192; lin += 256) {
        int t = lin >> 7, f4 = lin & 127;
        int idx = idxs[t];
        int b4 = f4 << 2;
        f32x4 v;
        v.x = (idx == b4)     ? 1.f : 0.f;
        v.y = (idx == b4 + 1) ? 1.f : 0.f;
        v.z = (idx == b4 + 2) ? 1.f : 0.f;
        v.w = (idx == b4 + 3) ? 1.f : 0.f;
        __builtin_nontemporal_store(v,
            (f32x4*)(out + OFF_ENC + ((size_t)(n0 + t) << 9) + (size_t)b4));
    }
    // quantized_words = codebook rows (L2-resident reads, NT writes)
    for (int lin = tid; lin < 8192; lin += 256) {
        int t = lin >> 7, f4 = lin & 127;
        f32x4 c4 = *(const f32x4*)(cw + (size_t)idxs[t] * DIM + (f4 << 2));
        __builtin_nontemporal_store(c4,
            (f32x4*)(out + OFF_QW + ((size_t)(n0 + t) << 9) + (size_t)(f4 << 2)));
    }
    // vq partial reduce
    for (int st = 128; st; st >>= 1) {
        if (tid < st) dred[tid] += dred[tid + st];
        __syncthreads();
    }
    if (tid == 0) atomicAdd(vq_acc, dred[0]);
}

// ---------------------------------------------------------------------------
// Exact fp32 recompute for flagged near-tie tokens; patches outputs in place.
__global__ __launch_bounds__(512)
void k_fixup(const int* __restrict__ doc, const float* __restrict__ emb,
             const float* __restrict__ cw, const float* __restrict__ n_arr,
             const unsigned* __restrict__ nflag, const unsigned* __restrict__ flag_list,
             float* __restrict__ out, unsigned* __restrict__ counts,
             double* __restrict__ vq_acc) {
    __shared__ float xs[512];
    __shared__ float nxsh;
    __shared__ int oldj_sh;
    __shared__ float vsh[512];
    __shared__ unsigned long long keys[512];

    const int tid = threadIdx.x;
    unsigned nf = *nflag;
    if (nf > FLAG_CAP) nf = FLAG_CAP;

    for (unsigned f = blockIdx.x; f < nf; f += gridDim.x) {
        int t = (int)flag_list[f];
        int dc = doc[t];
        if (tid < 128)
            *(float4*)&xs[tid * 4] = *(const float4*)(emb + (size_t)dc * DIM + tid * 4);
        if (tid == 0) oldj_sh = -1;
        __syncthreads();
        if (tid == 0) {
            double p[4];
            for (int q = 0; q < 4; ++q) {
                double px = 0.0;
                for (int fq = 0; fq < 32; ++fq) {
                    float4 v = *(const float4*)&xs[q * 128 + fq * 4];
                    px += (double)v.x*v.x + (double)v.y*v.y + (double)v.z*v.z + (double)v.w*v.w;
                }
                p[q] = px;
            }
            nxsh = (float)(((p[0] + p[1]) + p[2]) + p[3]);
        }
        {
            float e = out[OFF_ENC + (size_t)t * 512 + tid];
            if (e == 1.0f) oldj_sh = tid;
        }
        __syncthreads();
        {
            const float* cr = cw + (size_t)tid * DIM;
            float dot = 0.f;
            for (int d = 0; d < 512; ++d) dot = fmaf(xs[d], cr[d], dot);
            float v = fmaf(-2.f, dot, nxsh + n_arr[tid]);
            vsh[tid] = v;
            keys[tid] = (((unsigned long long)__float_as_uint(v)) << 32) | (unsigned)tid;
        }
        __syncthreads();
        for (int st = 256; st; st >>= 1) {
            if (tid < st) {
                unsigned long long o = keys[tid + st];
                if (o < keys[tid]) keys[tid] = o;
            }
            __syncthreads();
        }
        int newj = (int)(keys[0] & 0xffffffffu);
        int oldj = oldj_sh;
        if (newj != oldj) {
            if (tid == 0) {
                out[OFF_ENC + (size_t)t * 512 + oldj] = 0.0f;
                out[OFF_ENC + (size_t)t * 512 + newj] = 1.0f;
                atomicSub(&counts[oldj], 1u);
                atomicAdd(&counts[newj], 1u);
                atomicAdd(vq_acc, (double)vsh[newj] - (double)vsh[oldj]);
            }
            if (tid < 128) {
                float4 cn = *(const float4*)(cw + (size_t)newj * DIM + tid * 4);
                *(float4*)&out[OFF_QW + (size_t)t * 512 + tid * 4] = cn;
            }
        }
        __syncthreads();
    }
}

// ---------------------------------------------------------------------------
__global__ void k_binc(const int* __restrict__ doc, unsigned* __restrict__ binc) {
    int i = blockIdx.x * blockDim.x + threadIdx.x;
    if (i < N_TOK) atomicAdd(&binc[doc[i]], 1u);
}

__global__ void k_docu(const unsigned* __restrict__ counts,
                       const float* __restrict__ cw, float* __restrict__ out_docu) {
    __shared__ float cnt[512];
    int tid = threadIdx.x;
    cnt[tid] = (float)counts[tid];
    __syncthreads();
    double a = 0.0;
    for (int j = 0; j < K_CON; ++j)
        a += (double)cnt[j] * (double)cw[(size_t)j * DIM + tid];
    out_docu[tid] = (float)(a * (1.0 / (double)N_TOK));
}

__global__ __launch_bounds__(256)
void k_lts(const float* __restrict__ cw, const float* __restrict__ n_arr,
           const float* __restrict__ s_arr, double* __restrict__ lts_acc) {
    __shared__ float ci[4 * 512];
    __shared__ float cjs[64 * 68];
    __shared__ double dred[256];
    const int tid = threadIdx.x;
    const int i0 = blockIdx.x * 4;
    #pragma unroll
    for (int rep = 0; rep < 2; ++rep) {
        int lin = rep * 256 + tid;
        int r = lin >> 7, fq = lin & 127;
        *(float4*)&ci[r*512 + fq*4] = *(const float4*)(cw + (size_t)(i0+r)*DIM + fq*4);
    }
    const int jj = tid & 63, ih = tid >> 6;
    const int ig = i0 + ih;
    const float ni = n_arr[ig], si = s_arr[ig];
    const float EPS = 1e-6f;
    double lsum = 0.0;
    for (int jc = 0; jc < 8; ++jc) {
        float accv = 0.f;
        for (int dc = 0; dc < 8; ++dc) {
            __syncthreads();
            #pragma unroll
            for (int rep = 0; rep < 4; ++rep) {
                int lin = rep * 256 + tid;
                int j = lin >> 4, fq = lin & 15;
                float4 v = *(const float4*)(cw + (size_t)(jc*64 + j)*DIM + dc*64 + fq*4);
                cjs[(fq*4+0)*68 + j] = v.x; cjs[(fq*4+1)*68 + j] = v.y;
                cjs[(fq*4+2)*68 + j] = v.z; cjs[(fq*4+3)*68 + j] = v.w;
            }
            __syncthreads();
            #pragma unroll 4
            for (int d = 0; d < 64; ++d)
                accv = fmaf(ci[ih*512 + dc*64 + d], cjs[d*68 + jj], accv);
        }
        int jg = jc*64 + jj;
        float ddv = ni + n_arr[jg] - 2.f*accv + 2.f*EPS*(si - s_arr[jg]) + 512.f*EPS*EPS;
        float dist = sqrtf(fmaxf(ddv, 0.f));
        lsum += (double)((ig == jg) ? dist : fmaxf(0.f, 1.f - dist));
    }
    dred[tid] = lsum;
    __syncthreads();
    for (int s = 128; s; s >>= 1) {
        if (tid < s) dred[tid] += dred[tid + s];
        __syncthreads();
    }
    if (tid == 0) atomicAdd(lts_acc, dred[0]);
}

__global__ void k_logits(const float* __restrict__ docu, const float* __restrict__ q2w,
                         const float* __restrict__ q2b, float* __restrict__ logits) {
    int wvi = threadIdx.x >> 6, lane = threadIdx.x & 63;
    int v = blockIdx.x * 4 + wvi;
    if (v >= VOCAB) return;
    const float* wr = q2w + (size_t)v * DIM;
    float4 a = *(const float4*)(wr + lane*8);
    float4 b = *(const float4*)(wr + lane*8 + 4);
    float4 da = *(const float4*)(docu + lane*8);
    float4 db = *(const float4*)(docu + lane*8 + 4);
    float p = a.x*da.x + a.y*da.y + a.z*da.z + a.w*da.w
            + b.x*db.x + b.y*db.y + b.z*db.z + b.w*db.w;
    for (int off = 32; off; off >>= 1) p += __shfl_down(p, off);
    if (lane == 0) logits[v] = p + q2b[v];
}

// fused max + sum(exp) reduction over logits (single block)
__global__ void k_smred(const float* __restrict__ logits, float* __restrict__ maxv,
                        double* __restrict__ sumv) {
    __shared__ float redf[1024];
    __shared__ double redd[1024];
    int tid = threadIdx.x;
    float m = -INFINITY;
    for (int i = tid; i < VOCAB; i += 1024) m = fmaxf(m, logits[i]);
    redf[tid] = m; __syncthreads();
    for (int s = 512; s; s >>= 1) {
        if (tid < s) redf[tid] = fmaxf(redf[tid], redf[tid + s]);
        __syncthreads();
    }
    float mm = redf[0];
    if (tid == 0) *maxv = mm;
    double s = 0.0;
    for (int i = tid; i < VOCAB; i += 1024) s += (double)expf(logits[i] - mm);
    redd[tid] = s; __syncthreads();
    for (int st = 512; st; st >>= 1) {
        if (tid < st) redd[tid] += redd[tid + st];
        __syncthreads();
    }
    if (tid == 0) *sumv = redd[0];
}

__global__ void k_final(const float* __restrict__ logits, const float* __restrict__ maxv,
                        const double* __restrict__ sumv, const unsigned* __restrict__ binc,
                        const double* __restrict__ vq_acc, const double* __restrict__ lts_acc,
                        float* __restrict__ out) {
    int v = blockIdx.x * 256 + threadIdx.x;
    if (v < VOCAB) {
        float m = *maxv;
        float s = (float)(*sumv);
        float p = expf(logits[v] - m) / s;
        out[OFF_OUT + v] = logf(p + 1e-6f) * (float)binc[v];
    }
    if (v == 0) {
        out[OFF_VQ]  = (float)(1.25 * (*vq_acc) * (1.0 / 67108864.0));
        out[OFF_LTS] = (float)((*lts_acc) * (1.0 / 262144.0));
    }
}

// ---------------------------------------------------------------------------
extern "C" void kernel_launch(void* const* d_in, const int* in_sizes, int n_in,
                              void* d_out, int out_size, void* d_ws, size_t ws_size,
                              hipStream_t stream) {
    const int*   doc = (const int*)d_in[0];
    const float* emb = (const float*)d_in[1];
    const float* cw  = (const float*)d_in[2];
    const float* q2w = (const float*)d_in[3];
    const float* q2b = (const float*)d_in[4];
    float* out = (float*)d_out;
    char* ws = (char*)d_ws;

    unsigned* counts = (unsigned*)(ws + WS_COUNTS);
    double*   vq_acc = (double*)(ws + WS_VQ);
    double*   lts_acc= (double*)(ws + WS_LTS);
    float*    maxv   = (float*)(ws + WS_MAXV);
    double*   sumv   = (double*)(ws + WS_SUMV);
    unsigned* nflag  = (unsigned*)(ws + WS_NFLAG);
    float*    n_arr  = (float*)(ws + WS_NARR);
    float*    s_arr  = (float*)(ws + WS_SARR);
    unsigned* binc   = (unsigned*)(ws + WS_BINC);
    float*    logits = (float*)(ws + WS_LOGITS);
    unsigned* flags  = (unsigned*)(ws + WS_FLAGS);

    short* b2;
    hipGetSymbolAddress((void**)&b2, HIP_SYMBOL(g_B2));

    hipMemsetAsync(ws, 0, 4096, stream);
    hipMemsetAsync(binc, 0, VOCAB * sizeof(unsigned), stream);

    hipLaunchKernelGGL(k_ns,    dim3(128),  dim3(256), 0, stream, cw, n_arr, s_arr);
    hipLaunchKernelGGL(k_prepb, dim3(128),  dim3(256), 0, stream, cw, b2);
    hipLaunchKernelGGL(k_main,  dim3(2048), dim3(256), 0, stream, doc, emb, cw, n_arr,
                       out, counts, vq_acc, nflag, flags);
    hipLaunchKernelGGL(k_fixup, dim3(64),   dim3(512), 0, stream, doc, emb, cw, n_arr,
                       nflag, flags, out, counts, vq_acc);
    hipLaunchKernelGGL(k_binc,  dim3(512),  dim3(256), 0, stream, doc, binc);
    hipLaunchKernelGGL(k_docu,  dim3(1),    dim3(512), 0, stream, counts, cw, out + OFF_DOCU);
    hipLaunchKernelGGL(k_lts,   dim3(128),  dim3(256), 0, stream, cw, n_arr, s_arr, lts_acc);
    hipLaunchKernelGGL(k_logits, dim3((VOCAB + 3) / 4), dim3(256), 0, stream,
                       out + OFF_DOCU, q2w, q2b, logits);
    hipLaunchKernelGGL(k_smred, dim3(1), dim3(1024), 0, stream, logits, maxv, sumv);
    hipLaunchKernelGGL(k_final, dim3((VOCAB + 255) / 256), dim3(256), 0, stream,
                       logits, maxv, sumv, binc, vq_acc, lts_acc, out);
}